// Round 1
// baseline (996.285 us; speedup 1.0000x reference)
//
#include <hip/hip_runtime.h>

// MI355X / gfx950. Wave = 64. MFMA fp16 16x16x32.
// Verified layouts (m89/m91): A[m=lane&15][k=quad*8+j], B[n=lane&15][k=quad*8+j],
// C/D: col=lane&15, row=quad*4+reg. k-grouping permutation-invariant if A/B agree.

typedef _Float16 half8 __attribute__((ext_vector_type(8)));
typedef float    floatx4 __attribute__((ext_vector_type(4)));

#define MFMA16(a, b, c) __builtin_amdgcn_mfma_f32_16x16x32_f16((a), (b), (c), 0, 0, 0)

#define D_MODEL 1024
#define S_LEN   2048
#define NHEAD   16
#define DEPTH   64
#define BATCH   2

// async global->LDS, 16B per lane. LDS dest = wave-uniform base + lane*16;
// per-lane lds pointers below are constructed to satisfy exactly that.
__device__ __forceinline__ void gld_lds16(const _Float16* g, _Float16* l) {
    __builtin_amdgcn_global_load_lds(
        (const __attribute__((address_space(1))) unsigned int*)g,
        (__attribute__((address_space(3))) unsigned int*)l, 16, 0, 0);
}

// ---------------------------------------------------------------------------
// fp32 -> fp16 convert, 8 elements/thread.
// ---------------------------------------------------------------------------
__global__ void cvt_kernel(const float* __restrict__ src, _Float16* __restrict__ dst, int n8) {
    int i = blockIdx.x * 256 + threadIdx.x;
    if (i < n8) {
        const floatx4* s = (const floatx4*)src + (size_t)i * 2;
        floatx4 f0 = s[0], f1 = s[1];
        half8 h;
#pragma unroll
        for (int j = 0; j < 4; ++j) { h[j] = (_Float16)f0[j]; h[4 + j] = (_Float16)f1[j]; }
        *((half8*)dst + i) = h;
    }
}

// ---------------------------------------------------------------------------
// GEMM: Y = X @ W^T + b. X:[4096x1024] fp16, W:[1024x1024] fp16 (row-major).
// 128x128 tile, BK=32, 4 waves (2x2), global_load_lds width=16 (m97 structure).
// MODE 0: fp16 out, head-split [B][H][S][D]     (Q, K projections)
// MODE 2: fp16 out, head-split transposed [B][H][D][S]  (V projection)
// MODE 1: fp32 out, [4096][1024]                (final projection)
// ---------------------------------------------------------------------------
template <int MODE>
__global__ __launch_bounds__(256) void gemm_kernel(
    const _Float16* __restrict__ X, const _Float16* __restrict__ W,
    const float* __restrict__ bias, void* __restrict__ outp)
{
    __shared__ _Float16 A_lds[128 * 32];   // unpadded: required by global_load_lds
    __shared__ _Float16 B_lds[128 * 32];

    const int tid  = threadIdx.x;
    const int lane = tid & 63;
    const int w    = tid >> 6;
    const int r15  = lane & 15;
    const int quad = lane >> 4;
    const int wr   = w >> 1, wc = w & 1;
    const int bn   = blockIdx.x;           // 0..7
    const int bm   = blockIdx.y;           // 0..31

    // staging: issue j covers rows j*64 + w*16 + lane/4, 16B segment lane&3
    const int srow = w * 16 + (lane >> 2);
    const int sseg = lane & 3;
    const _Float16* ag = X + (size_t)(bm * 128 + srow) * 1024 + sseg * 8;
    const _Float16* bg = W + (size_t)(bn * 128 + srow) * 1024 + sseg * 8;
    _Float16* al = &A_lds[srow * 32 + sseg * 8];
    _Float16* bl = &B_lds[srow * 32 + sseg * 8];

    floatx4 acc[4][4];
#pragma unroll
    for (int t = 0; t < 4; ++t)
#pragma unroll
        for (int u = 0; u < 4; ++u) acc[t][u] = floatx4{0.f, 0.f, 0.f, 0.f};

    for (int k0 = 0; k0 < 1024; k0 += 32) {
        __syncthreads();                               // prev iter frag reads done
        gld_lds16(ag + k0, al);
        gld_lds16(ag + k0 + (size_t)64 * 1024, al + 64 * 32);
        gld_lds16(bg + k0, bl);
        gld_lds16(bg + k0 + (size_t)64 * 1024, bl + 64 * 32);
        __syncthreads();                               // loads landed (vmcnt drain)
        half8 a[4], bf[4];
#pragma unroll
        for (int t = 0; t < 4; ++t)
            a[t] = *(const half8*)&A_lds[(wr * 64 + t * 16 + r15) * 32 + quad * 8];
#pragma unroll
        for (int u = 0; u < 4; ++u)
            bf[u] = *(const half8*)&B_lds[(wc * 64 + u * 16 + r15) * 32 + quad * 8];
#pragma unroll
        for (int t = 0; t < 4; ++t)
#pragma unroll
            for (int u = 0; u < 4; ++u) acc[t][u] = MFMA16(a[t], bf[u], acc[t][u]);
    }

    const int gc0 = bn * 128 + wc * 64;
    float bb[4];
#pragma unroll
    for (int u = 0; u < 4; ++u) bb[u] = bias[gc0 + u * 16 + r15];

#pragma unroll
    for (int t = 0; t < 4; ++t) {
#pragma unroll
        for (int u = 0; u < 4; ++u) {
            const int gc = gc0 + u * 16 + r15;
#pragma unroll
            for (int r = 0; r < 4; ++r) {
                const int grow = bm * 128 + wr * 64 + t * 16 + quad * 4 + r;
                const float val = acc[t][u][r] + bb[u];
                if constexpr (MODE == 0) {
                    const int hh = gc >> 6, dd = gc & 63;
                    const int b_ = grow >> 11, s = grow & 2047;
                    ((_Float16*)outp)[((size_t)((b_ * 16 + hh) * 2048 + s)) * 64 + dd] =
                        (_Float16)val;
                } else if constexpr (MODE == 2) {
                    const int hh = gc >> 6, dd = gc & 63;
                    const int b_ = grow >> 11, s = grow & 2047;
                    ((_Float16*)outp)[((size_t)((b_ * 16 + hh) * 64 + dd)) * 2048 + s] =
                        (_Float16)val;
                } else {
                    ((float*)outp)[(size_t)grow * 1024 + gc] = val;
                }
            }
        }
    }
}

// ---------------------------------------------------------------------------
// Attention, flash-style two-pass over keys to kill register pressure.
// Block = (b, h, 16 q-rows), 4 waves splitting keys (wv*16+r15).
//
// Pass A: online softmax stats (m, l) per q-row — only one z tile live at a
//   time -> ~70 VGPRs instead of 128-reg S[32] -> 4 blocks/CU (was 2).
// Pass B: recompute QK^T per 64-key tile (MFMA was 3.8% util, K is L2-hot),
//   w = exp(z*scale - gm)*gli; fp32 weights stored NONTEMPORAL (536 MB stream
//   must not evict K/V from L2); fp16 w staged through a tiny 2x2.3KB
//   double-buffered LDS tile (stride 72 = conflict-free transpose) for PV.
//   Hot-loop barrier = lgkmcnt(0) + raw s_barrier: producer LDS drain only,
//   global loads/stores stay in flight across all 32 barriers (no vmcnt(0)).
// XCD swizzle: 4096 blocks -> each XCD owns 512 consecutive work items =
//   4 heads of K/V (2 MB) -> fits private 4 MB L2.
// mask*1e-9 contribution dropped (<=1e-9 on O(1) logits).
// ---------------------------------------------------------------------------
__global__ __launch_bounds__(256, 4) void attn_kernel(
    const _Float16* __restrict__ Q, const _Float16* __restrict__ K,
    const _Float16* __restrict__ Vt, float* __restrict__ wout,
    _Float16* __restrict__ attn_out)
{
    __shared__ _Float16 w_s[2][16 * 72];   // double-buffered 16 rows x 64 keys (+8 pad)
    __shared__ float red_m[4][16];
    __shared__ float red_l[4][16];

    const int tid  = threadIdx.x;
    const int lane = tid & 63;
    const int wv   = tid >> 6;
    const int r15  = lane & 15;
    const int quad = lane >> 4;

    // XCD-aware swizzle (4096 % 8 == 0 -> bijective)
    const int orig = blockIdx.x + 128 * (blockIdx.y + 16 * blockIdx.z);
    const int work = (orig & 7) * 512 + (orig >> 3);
    const int qb = work & 127;
    const int h  = (work >> 7) & 15;
    const int b  = work >> 11;

    const size_t hoff = ((size_t)(b * 16 + h)) * S_LEN * DEPTH;
    const _Float16* Qh  = Q + hoff + (size_t)qb * 16 * DEPTH;
    const _Float16* Kh  = K + hoff;
    const _Float16* Vth = Vt + hoff;     // [d][s] layout per head

    half8 q0 = *(const half8*)(Qh + r15 * 64 + quad * 8);
    half8 q1 = *(const half8*)(Qh + r15 * 64 + 32 + quad * 8);

    const _Float16* kbase = Kh + (size_t)(wv * 16 + r15) * 64 + quad * 8;

    // ---- Pass A: online (m, l) over all 2048 keys, one 64-key tile at a time
    float m[4], l[4];
#pragma unroll
    for (int j = 0; j < 4; ++j) { m[j] = -1e30f; l[j] = 0.f; }

#pragma unroll 4
    for (int kt = 0; kt < 32; ++kt) {
        const _Float16* kp = kbase + (size_t)kt * 4096;
        half8 b0 = *(const half8*)kp;
        half8 b1 = *(const half8*)(kp + 32);
        floatx4 z = floatx4{0.f, 0.f, 0.f, 0.f};
        z = MFMA16(q0, b0, z);
        z = MFMA16(q1, b1, z);
#pragma unroll
        for (int j = 0; j < 4; ++j) {
            float s  = z[j] * 0.125f;                 // 1/sqrt(64)
            float nm = fmaxf(m[j], s);
            l[j] = l[j] * __expf(m[j] - nm) + __expf(s - nm);
            m[j] = nm;
        }
    }
    // reduce over the 16 key-lanes (r15) of this wave
#pragma unroll
    for (int mk = 1; mk <= 8; mk <<= 1)
#pragma unroll
        for (int j = 0; j < 4; ++j) {
            float om = __shfl_xor(m[j], mk, 64);
            float ol = __shfl_xor(l[j], mk, 64);
            float nm = fmaxf(m[j], om);
            l[j] = l[j] * __expf(m[j] - nm) + ol * __expf(om - nm);
            m[j] = nm;
        }
    // cross-wave reduce via tiny LDS
#pragma unroll
    for (int j = 0; j < 4; ++j)
        if (r15 == j) { red_m[wv][quad * 4 + j] = m[j]; red_l[wv][quad * 4 + j] = l[j]; }
    __syncthreads();
    float gm[4], gli[4];
#pragma unroll
    for (int j = 0; j < 4; ++j) {
        const int row = quad * 4 + j;
        float m0 = red_m[0][row], m1 = red_m[1][row];
        float m2 = red_m[2][row], m3 = red_m[3][row];
        float mm = fmaxf(fmaxf(m0, m1), fmaxf(m2, m3));
        float ll = red_l[0][row] * __expf(m0 - mm) + red_l[1][row] * __expf(m1 - mm)
                 + red_l[2][row] * __expf(m2 - mm) + red_l[3][row] * __expf(m3 - mm);
        gm[j]  = mm;
        gli[j] = 1.0f / ll;
    }

    // ---- Pass B: recompute logits per tile, write weights, PV ----
    float* wrow = wout + (((size_t)(b * 16 + h)) * S_LEN + (size_t)qb * 16) * S_LEN;
    const _Float16* vbase = Vth + (size_t)(wv * 16 + r15) * 2048 + quad * 8;
    floatx4 oacc = floatx4{0.f, 0.f, 0.f, 0.f};

    for (int kt = 0; kt < 32; ++kt) {
        const _Float16* kp = kbase + (size_t)kt * 4096;
        half8 kb0 = *(const half8*)kp;
        half8 kb1 = *(const half8*)(kp + 32);
        const _Float16* vp = vbase + (size_t)kt * 64;
        half8 vb0 = *(const half8*)vp;
        half8 vb1 = *(const half8*)(vp + 32);

        floatx4 z = floatx4{0.f, 0.f, 0.f, 0.f};
        z = MFMA16(q0, kb0, z);
        z = MFMA16(q1, kb1, z);

        _Float16* ws = &w_s[kt & 1][0];
#pragma unroll
        for (int j = 0; j < 4; ++j) {
            float e = __expf(z[j] * 0.125f - gm[j]) * gli[j];
            ws[(quad * 4 + j) * 72 + wv * 16 + r15] = (_Float16)e;
            __builtin_nontemporal_store(
                e, &wrow[(size_t)(quad * 4 + j) * 2048 + kt * 64 + wv * 16 + r15]);
        }
        // producer-side LDS drain only; global loads/stores stay in flight
        asm volatile("s_waitcnt lgkmcnt(0)" ::: "memory");
        __builtin_amdgcn_s_barrier();
        __builtin_amdgcn_sched_barrier(0);

        half8 a0 = *(const half8*)&ws[r15 * 72 + quad * 8];
        half8 a1 = *(const half8*)&ws[r15 * 72 + 32 + quad * 8];
        oacc = MFMA16(a0, vb0, oacc);
        oacc = MFMA16(a1, vb1, oacc);
        // no trailing barrier: next iter writes the other buffer; this wave's
        // reads drain at the next lgkmcnt(0) before anyone rewrites this one.
    }

    // attn output fp16, [b*2048+s][h*64+d]  (GEMM input for Wo)
    _Float16* ao = attn_out + ((size_t)(b * S_LEN + qb * 16)) * D_MODEL + h * 64 + wv * 16;
#pragma unroll
    for (int r = 0; r < 4; ++r)
        ao[(size_t)(quad * 4 + r) * D_MODEL + r15] = (_Float16)oacc[r];
}

// ---------------------------------------------------------------------------
extern "C" void kernel_launch(void* const* d_in, const int* in_sizes, int n_in,
                              void* d_out, int out_size, void* d_ws, size_t ws_size,
                              hipStream_t stream)
{
    const float* q  = (const float*)d_in[0];
    const float* k  = (const float*)d_in[1];
    const float* v  = (const float*)d_in[2];
    // d_in[3] = mask: mask*1e-9 <= 1e-9 on O(1) logits -> numerically dropped.
    const float* Wq = (const float*)d_in[4];
    const float* bq = (const float*)d_in[5];
    const float* Wk = (const float*)d_in[6];
    const float* bk = (const float*)d_in[7];
    const float* Wv = (const float*)d_in[8];
    const float* bv = (const float*)d_in[9];
    const float* Wo = (const float*)d_in[10];
    const float* bo = (const float*)d_in[11];

    const size_t NTOK = (size_t)BATCH * S_LEN * D_MODEL;   // 4194304
    const size_t WSZ  = (size_t)D_MODEL * D_MODEL;         // 1048576
    _Float16* base = (_Float16*)d_ws;
    _Float16* qh  = base;                 // fp16 X inputs (qh reused as Aw later)
    _Float16* kh  = base + NTOK;
    _Float16* vh  = base + 2 * NTOK;
    _Float16* Qw  = base + 3 * NTOK;      // projected Q [b,h,s,d]
    _Float16* Kw  = base + 4 * NTOK;      // projected K [b,h,s,d]
    _Float16* Vt  = base + 5 * NTOK;      // projected V [b,h,d,s]
    _Float16* Wqh = base + 6 * NTOK;
    _Float16* Wkh = Wqh + WSZ;
    _Float16* Wvh = Wkh + WSZ;
    _Float16* Woh = Wvh + WSZ;
    _Float16* Aw  = qh;                   // attention output (qh no longer needed)

    float* out  = (float*)d_out;          // [2,2048,1024]
    float* wout = out + NTOK;             // [2,16,2048,2048]

    dim3 blk(256);
    cvt_kernel<<<dim3(2048), blk, 0, stream>>>(q, qh, (int)(NTOK / 8));
    cvt_kernel<<<dim3(2048), blk, 0, stream>>>(k, kh, (int)(NTOK / 8));
    cvt_kernel<<<dim3(2048), blk, 0, stream>>>(v, vh, (int)(NTOK / 8));
    cvt_kernel<<<dim3(512),  blk, 0, stream>>>(Wq, Wqh, (int)(WSZ / 8));
    cvt_kernel<<<dim3(512),  blk, 0, stream>>>(Wk, Wkh, (int)(WSZ / 8));
    cvt_kernel<<<dim3(512),  blk, 0, stream>>>(Wv, Wvh, (int)(WSZ / 8));
    cvt_kernel<<<dim3(512),  blk, 0, stream>>>(Wo, Woh, (int)(WSZ / 8));

    dim3 ggrid(8, 32);
    gemm_kernel<0><<<ggrid, blk, 0, stream>>>(qh, Wqh, bq, (void*)Qw);
    gemm_kernel<0><<<ggrid, blk, 0, stream>>>(kh, Wkh, bk, (void*)Kw);
    gemm_kernel<2><<<ggrid, blk, 0, stream>>>(vh, Wvh, bv, (void*)Vt);

    attn_kernel<<<dim3(128, 16, 2), blk, 0, stream>>>(Qw, Kw, Vt, wout, Aw);

    gemm_kernel<1><<<ggrid, blk, 0, stream>>>(Aw, Woh, bo, (void*)out);
}